// Round 16
// baseline (60.639 us; speedup 1.0000x reference)
//
#include <hip/hip_runtime.h>
#include <hip/hip_bf16.h>

// ClusterAggregator: B=8, N=32768, D=128, C=64, H=64
// out[b,c,:] = sum_{n: ca[b,n]==c} w_n * f[b,n,:], w = segment softmax of
// imp = sigmoid(relu(f@W1+b1)@W2+b2). Softmax shift-invariance: fixed shift 1.
//
// R16: 256-thread re-cut. Every 512-thread build allocated VGPR=64 and
// spilled the ~115-reg live set (R8/R10/R11: WRITE_SIZE 38-45MB vs 17
// expected) -- attributes couldn't override; 256-thread builds historically
// allocate 80-128 (R1/R2/R6) with clean WRITE_SIZE. Same algorithm as R12:
// 1024 blocks x 4 waves, 64-row super-steps, register prefetch 1 ss ahead,
// one-hot MFMA aggregation; phase-B split re-mapped for 4 waves
// (wave = (c-half, d-half), accS 8 frags, accD for c4=wave).

#define B_ 8
#define N_ 32768
#define D_ 128
#define C_ 64
#define H_ 64

#define NTHREADS 256
#define NWAVES 4
#define ROWS_PER_BLOCK 256
#define NBLOCKS ((B_ * N_) / ROWS_PER_BLOCK)   // 1024
#define SLICES (NBLOCKS / B_)                  // 128 per batch
#define NSS 4                                  // super-steps of 64 rows
#define RST2 72   // ft ushort stride (144 B: 16B-aligned; slot = m+kb mod 8)
#define W1S 136   // w1l ushort stride

typedef float f32x4 __attribute__((ext_vector_type(4)));
typedef short s16x8 __attribute__((ext_vector_type(8)));

__device__ __forceinline__ short bf16rne(float x) {
    unsigned u = __float_as_uint(x);
    u = (u + 0x7FFFu + ((u >> 16) & 1u)) >> 16;
    return (short)u;
}

__device__ __forceinline__ s16x8 pk8(float4 a, float4 b) {
    union { s16x8 v; __hip_bfloat162 h[4]; } u;
    u.h[0] = __float22bfloat162_rn(make_float2(a.x, a.y));
    u.h[1] = __float22bfloat162_rn(make_float2(a.z, a.w));
    u.h[2] = __float22bfloat162_rn(make_float2(b.x, b.y));
    u.h[3] = __float22bfloat162_rn(make_float2(b.z, b.w));
    return u.v;
}

template <bool USE_WS>
__global__ __launch_bounds__(NTHREADS, 4)   // 4 waves/EU (4 blocks/CU via LDS)
void ca_fused_kernel(const float* __restrict__ features,
                     const int* __restrict__ ca,
                     const float* __restrict__ b1,
                     const float* __restrict__ W2,
                     const float* __restrict__ b2,
                     const float* __restrict__ W1,   // fp32 [128][64]
                     float* __restrict__ out_sums,   // atomic path: [B*C*D]
                     float* __restrict__ denoms,     // atomic path: [B*C]
                     float* __restrict__ pout,       // ws path: [NBLOCKS][C*D]
                     float* __restrict__ pden)       // ws path: [NBLOCKS][C]
{
    __shared__ __align__(16) unsigned short ft[D_ * RST2];  // 18.4 KB bf16 f^T
    __shared__ __align__(16) unsigned short w1l[H_ * W1S];  // 17.4 KB bf16 W1^T
    __shared__ __align__(16) unsigned int ceu[64];          // packed (e|c)/row

    const int tid  = threadIdx.x;
    const int lane = tid & 63;
    const int wave = tid >> 6;     // 0..3
    const int m    = lane & 15;
    const int kb   = lane >> 4;
    const int kbase = kb * 8;
    const int bidx = blockIdx.x;
    const int b    = bidx / SLICES;
    const int row_blk0 = bidx * ROWS_PER_BLOCK;

    // W1 (fp32, coalesced) -> bf16 W1^T in LDS: w1l[h][k] = bf16(W1[k][h])
    for (int i = tid; i < H_ * D_; i += NTHREADS) {
        const int k = i >> 6, h = i & 63;
        w1l[h * W1S + k] = (unsigned short)bf16rne(W1[i]);
    }

    float b1v[4], w2v[4];
#pragma unroll
    for (int nt = 0; nt < 4; ++nt) {
        b1v[nt] = b1[nt * 16 + m];
        w2v[nt] = W2[nt * 16 + m];
    }
    const float b2v = b2[0];

    // 4-wave phase-B split: wave = (CH2 = c-half, dh = d-half)
    const int CH2 = wave >> 1;         // clusters [CH2*32, CH2*32+32)
    const int dh  = wave & 1;          // d-cols   [dh*64, dh*64+64)
    const int c4a = CH2 * 2;           // first 16-cluster chunk
    const int c4b = CH2 * 2 + 1;       // second 16-cluster chunk

    f32x4 accSa[4], accSb[4];
    f32x4 accD = (f32x4){0.f, 0.f, 0.f, 0.f};   // denominators for c4 = wave
#pragma unroll
    for (int nt = 0; nt < 4; ++nt) {
        accSa[nt] = (f32x4){0.f, 0.f, 0.f, 0.f};
        accSb[nt] = (f32x4){0.f, 0.f, 0.f, 0.f};
    }

    // ones-column B fragment for denominator MFMA: B[k][n] = (n==0)
    s16x8 bones;
    {
        const short o = (m == 0) ? (short)0x3F80 : (short)0;
#pragma unroll
        for (int j = 0; j < 8; ++j) bones[j] = o;
    }

    // ---- register prefetch for super-step 0: lane owns row wave*16+m ----
    const float* fbase = features + (long long)(row_blk0 + wave * 16 + m) * D_;
    float4 pf[8];
#pragma unroll
    for (int ks = 0; ks < 4; ++ks) {
        pf[2 * ks]     = *(const float4*)(fbase + ks * 32 + kbase);
        pf[2 * ks + 1] = *(const float4*)(fbase + ks * 32 + kbase + 4);
    }
    int cv = 0;
    if (lane < 16) cv = ca[row_blk0 + wave * 16 + lane];

    __syncthreads();   // w1l ready

#pragma unroll
    for (int ss = 0; ss < NSS; ++ss) {
        // consume prefetch -> bf16 A-frags
        s16x8 af[4];
#pragma unroll
        for (int ks = 0; ks < 4; ++ks) af[ks] = pk8(pf[2 * ks], pf[2 * ks + 1]);
        const int cvc = cv;

        // issue prefetch for next super-step (in flight through A+B)
        if (ss + 1 < NSS) {
            const float* fn = fbase + (ss + 1) * 64 * D_;
#pragma unroll
            for (int ks = 0; ks < 4; ++ks) {
                pf[2 * ks]     = *(const float4*)(fn + ks * 32 + kbase);
                pf[2 * ks + 1] = *(const float4*)(fn + ks * 32 + kbase + 4);
            }
            if (lane < 16) cv = ca[row_blk0 + (ss + 1) * 64 + wave * 16 + lane];
        }

        // ---- phase A: stage ft (transposed bf16) + h-matmul + epilogue ----
        const int r = wave * 16 + m;   // row within 64-row super-tile
#pragma unroll
        for (int ks = 0; ks < 4; ++ks)
#pragma unroll
            for (int j = 0; j < 8; ++j)
                ft[(ks * 32 + kbase + j) * RST2 + r] = (unsigned short)af[ks][j];

        f32x4 hacc[4];
#pragma unroll
        for (int nt = 0; nt < 4; ++nt) hacc[nt] = (f32x4){0.f, 0.f, 0.f, 0.f};
#pragma unroll
        for (int ks = 0; ks < 4; ++ks)
#pragma unroll
            for (int nt = 0; nt < 4; ++nt) {
                const s16x8 w = *(const s16x8*)&w1l[(nt * 16 + m) * W1S +
                                                    ks * 32 + kbase];
                hacc[nt] = __builtin_amdgcn_mfma_f32_16x16x32_bf16(
                    af[ks], w, hacc[nt], 0, 0, 0);
            }

        // relu, @W2, sigmoid, e = exp(imp-1)   (HW-validated path)
        float p[4];
#pragma unroll
        for (int rr = 0; rr < 4; ++rr) {
            float sv = 0.f;
#pragma unroll
            for (int nt = 0; nt < 4; ++nt)
                sv = fmaf(fmaxf(hacc[nt][rr] + b1v[nt], 0.f), w2v[nt], sv);
#pragma unroll
            for (int off = 1; off < 16; off <<= 1)
                sv += __shfl_xor(sv, off, 64);
            const float pre = sv + b2v;
            const float imp = 1.f / (1.f + __expf(-pre));
            p[rr] = __expf(imp - 1.f);
        }
        const int q = lane & 3;
        const float prov = (q == 0) ? p[0] : (q == 1) ? p[1] : (q == 2) ? p[2] : p[3];
        const int srcl = ((m >> 2) << 4) | (m & 3);
        const float eL = __shfl(prov, srcl, 64);   // e for local row (lane&15)
        if (lane < 16)
            ceu[wave * 16 + lane] =
                ((unsigned)(unsigned short)bf16rne(eL) << 16) | (unsigned)cvc;

        __syncthreads();   // ft + ceu complete for all 64 rows

        // ---- phase B: 2 k-groups of 32 rows; wave's (CH2, dh) slice ----
#pragma unroll
        for (int kg = 0; kg < 2; ++kg) {
            const uint4* cq = (const uint4*)&ceu[kg * 32 + kbase];
            const uint4 ua = cq[0], ub = cq[1];
            const unsigned uu[8] = {ua.x, ua.y, ua.z, ua.w, ub.x, ub.y, ub.z, ub.w};

            s16x8 afrA, afrB;
#pragma unroll
            for (int j = 0; j < 8; ++j) {
                const int cj = (int)(uu[j] & 0xFFu);
                const short ej = (short)(uu[j] >> 16);
                afrA[j] = (cj == c4a * 16 + m) ? ej : (short)0;
                afrB[j] = (cj == c4b * 16 + m) ? ej : (short)0;
            }

#pragma unroll
            for (int nt = 0; nt < 4; ++nt) {
                const int d0 = dh * 64 + nt * 16 + m;
                const s16x8 bfv = *(const s16x8*)&ft[d0 * RST2 + kg * 32 + kbase];
                accSa[nt] = __builtin_amdgcn_mfma_f32_16x16x32_bf16(
                    afrA, bfv, accSa[nt], 0, 0, 0);
                accSb[nt] = __builtin_amdgcn_mfma_f32_16x16x32_bf16(
                    afrB, bfv, accSb[nt], 0, 0, 0);
            }
            // denominators: this wave owns c4 = wave (== c4a if dh==0 else c4b)
            accD = __builtin_amdgcn_mfma_f32_16x16x32_bf16(
                (dh == 0) ? afrA : afrB, bones, accD, 0, 0, 0);
        }
        __syncthreads();   // ft/ceu reusable next super-step
    }

    // ---- flush: per-wave slices disjoint -> plain stores (ws path) ----
#pragma unroll
    for (int nt = 0; nt < 4; ++nt)
#pragma unroll
        for (int qq = 0; qq < 4; ++qq) {
            const int d0  = dh * 64 + nt * 16 + m;
            const int ia = (c4a * 16 + kb * 4 + qq) * D_ + d0;
            const int ib = (c4b * 16 + kb * 4 + qq) * D_ + d0;
            if (USE_WS) {
                pout[(size_t)bidx * (C_ * D_) + ia] = accSa[nt][qq];
                pout[(size_t)bidx * (C_ * D_) + ib] = accSb[nt][qq];
            } else {
                atomicAdd(&out_sums[b * (C_ * D_) + ia], accSa[nt][qq]);
                atomicAdd(&out_sums[b * (C_ * D_) + ib], accSb[nt][qq]);
            }
        }
    if (m == 0) {
#pragma unroll
        for (int qq = 0; qq < 4; ++qq) {
            const int c = wave * 16 + kb * 4 + qq;
            if (USE_WS) pden[bidx * C_ + c] = accD[qq];
            else atomicAdd(&denoms[b * C_ + c], accD[qq]);
        }
    }
}

// Reduce SLICES partials per (b,c), divide by reduced denom, write out.
__global__ __launch_bounds__(512)
void ca_reduce_kernel(const float* __restrict__ pout,
                      const float* __restrict__ pden,
                      float* __restrict__ out)
{
    __shared__ float red[512];
    __shared__ float redD[2];

    const int bc = blockIdx.x;           // 0 .. B_*C_-1
    const int b  = bc >> 6;
    const int c  = bc & (C_ - 1);
    const int t  = threadIdx.x;
    const int d  = t & 127;
    const int sg = t >> 7;               // 0..3

    const float* pb = pout + ((size_t)(b * SLICES + sg * 32)) * (C_ * D_)
                           + c * D_ + d;
    float s = 0.f;
#pragma unroll 4
    for (int i = 0; i < 32; ++i) s += pb[(size_t)i * (C_ * D_)];
    red[t] = s;

    if (t < 128) {
        float dnv = pden[(b * SLICES + t) * C_ + c];
#pragma unroll
        for (int off = 32; off > 0; off >>= 1) dnv += __shfl_xor(dnv, off, 64);
        if ((t & 63) == 0) redD[t >> 6] = dnv;
    }
    __syncthreads();

    if (t < 128) {
        const float tot = red[t] + red[t + 128] + red[t + 256] + red[t + 384];
        const float dn = redD[0] + redD[1];
        out[(size_t)bc * D_ + t] = (dn > 0.f) ? (tot / dn) : 0.f;
    }
}

__global__ void ca_zero_kernel(float* __restrict__ out_sums,
                               float* __restrict__ denoms)
{
    const int i = blockIdx.x * blockDim.x + threadIdx.x;
    if (i < B_ * C_ * D_) out_sums[i] = 0.f;
    if (i < B_ * C_)      denoms[i] = 0.f;
}

__global__ void ca_finalize_kernel(float* __restrict__ out_sums,
                                   const float* __restrict__ denoms)
{
    const int i = blockIdx.x * blockDim.x + threadIdx.x;
    if (i >= B_ * C_ * D_) return;
    const int bc = i >> 7;
    const float den = denoms[bc];
    const float v = out_sums[i];
    out_sums[i] = (den > 0.f) ? (v / den) : 0.f;
}

extern "C" void kernel_launch(void* const* d_in, const int* in_sizes, int n_in,
                              void* d_out, int out_size, void* d_ws, size_t ws_size,
                              hipStream_t stream) {
    const float* features = (const float*)d_in[0];
    const int*   ca       = (const int*)  d_in[1];
    const float* W1       = (const float*)d_in[2];
    const float* b1       = (const float*)d_in[3];
    const float* W2       = (const float*)d_in[4];
    const float* b2       = (const float*)d_in[5];

    float* out = (float*)d_out;   // [B*C*D]

    // ws layout: [pden 256KB][pout 32MB]
    float* pden = (float*)d_ws;
    float* pout = (float*)((char*)d_ws + (size_t)NBLOCKS * C_ * 4);
    const size_t need_full =
        (size_t)NBLOCKS * C_ * 4 + (size_t)NBLOCKS * C_ * D_ * 4;

    if (ws_size >= need_full) {
        ca_fused_kernel<true><<<NBLOCKS, NTHREADS, 0, stream>>>(
            features, ca, b1, W2, b2, W1, nullptr, nullptr, pout, pden);
        ca_reduce_kernel<<<B_ * C_, 512, 0, stream>>>(pout, pden, out);
    } else {
        // fallback: global-atomic flush (needs only pden prefix)
        ca_zero_kernel<<<(B_ * C_ * D_ + 255) / 256, 256, 0, stream>>>(out, pden);
        ca_fused_kernel<false><<<NBLOCKS, NTHREADS, 0, stream>>>(
            features, ca, b1, W2, b2, W1, out, pden, nullptr, nullptr);
        ca_finalize_kernel<<<(B_ * C_ * D_ + 255) / 256, 256, 0, stream>>>(out, pden);
    }
}

// Round 17
// 47.297 us; speedup vs baseline: 1.2821x; 1.2821x over previous
//
#include <hip/hip_runtime.h>
#include <hip/hip_bf16.h>

// ClusterAggregator: B=8, N=32768, D=128, C=64, H=64
// out[b,c,:] = sum_{n: ca[b,n]==c} w_n * f[b,n,:], w = segment softmax of
// imp = sigmoid(relu(f@W1+b1)@W2+b2). Softmax shift-invariance: fixed shift 1.
//
// R17 = R15 with __launch_bounds__(512, 2). 16-round correlation: every
// min-waves-per-EU=4 build (R7-R16, any block size) allocated VGPR=64 and
// spilled ~115-reg live set (WRITE_SIZE +21-52MB); every =2 build (R1/R2/R6)
// allocated 80-128 cleanly. LDS (56.8KB) already caps occupancy at 2
// blocks/CU = 16 waves/CU, and 128-VGPR waves still fit 16/CU -- so the
// relaxed bound frees the register allocator without costing occupancy.

#define B_ 8
#define N_ 32768
#define D_ 128
#define C_ 64
#define H_ 64

#define NTHREADS 512
#define NWAVES 8
#define ROWS_PER_BLOCK 512
#define NBLOCKS ((B_ * N_) / ROWS_PER_BLOCK)   // 512
#define SLICES (NBLOCKS / B_)                  // 64
#define NSS 4                                  // super-steps of 128 rows
#define RST 152   // ft ushort stride (304 B; 16B-aligned; LDS > 160K/3)
#define W1S 136   // w1l ushort stride

typedef float f32x4 __attribute__((ext_vector_type(4)));
typedef short s16x8 __attribute__((ext_vector_type(8)));

__device__ __forceinline__ short bf16rne(float x) {
    unsigned u = __float_as_uint(x);
    u = (u + 0x7FFFu + ((u >> 16) & 1u)) >> 16;
    return (short)u;
}

__device__ __forceinline__ s16x8 pk8(float4 a, float4 b) {
    union { s16x8 v; __hip_bfloat162 h[4]; } u;
    u.h[0] = __float22bfloat162_rn(make_float2(a.x, a.y));
    u.h[1] = __float22bfloat162_rn(make_float2(a.z, a.w));
    u.h[2] = __float22bfloat162_rn(make_float2(b.x, b.y));
    u.h[3] = __float22bfloat162_rn(make_float2(b.z, b.w));
    return u.v;
}

template <bool USE_WS>
__global__ __launch_bounds__(NTHREADS, 2)   // min 2 waves/EU: frees allocator
void ca_fused_kernel(const float* __restrict__ features,
                     const int* __restrict__ ca,
                     const float* __restrict__ b1,
                     const float* __restrict__ W2,
                     const float* __restrict__ b2,
                     const float* __restrict__ W1,   // fp32 [128][64]
                     float* __restrict__ out_sums,   // atomic path: [B*C*D]
                     float* __restrict__ denoms,     // atomic path: [B*C]
                     float* __restrict__ pout,       // ws path: [NBLOCKS][C*D]
                     float* __restrict__ pden)       // ws path: [NBLOCKS][C]
{
    __shared__ __align__(16) unsigned short ft[D_ * RST];   // 38.9 KB bf16 f^T
    __shared__ __align__(16) unsigned short w1l[H_ * W1S];  // 17.4 KB bf16 W1^T
    __shared__ __align__(16) unsigned int ceu[128];         // packed (e|c)/row

    const int tid  = threadIdx.x;
    const int lane = tid & 63;
    const int wave = tid >> 6;
    const int m    = lane & 15;
    const int kb   = lane >> 4;
    const int kbase = kb * 8;
    const int bidx = blockIdx.x;
    const int b    = bidx / SLICES;
    const int row_blk0 = bidx * ROWS_PER_BLOCK;

    // W1 (fp32, coalesced) -> bf16 W1^T in LDS: w1l[h][k] = bf16(W1[k][h])
    for (int i = tid; i < H_ * D_; i += NTHREADS) {
        const int k = i >> 6, h = i & 63;
        w1l[h * W1S + k] = (unsigned short)bf16rne(W1[i]);
    }

    float b1v[4], w2v[4];
#pragma unroll
    for (int nt = 0; nt < 4; ++nt) {
        b1v[nt] = b1[nt * 16 + m];
        w2v[nt] = W2[nt * 16 + m];
    }
    const float b2v = b2[0];

    const int CH = wave >> 1;   // this wave's cluster chunk (16 clusters)
    const int dh = wave & 1;    // this wave's d-half (64 dims)

    f32x4 accS[4];
    f32x4 accD = (f32x4){0.f, 0.f, 0.f, 0.f};
#pragma unroll
    for (int nt = 0; nt < 4; ++nt) accS[nt] = (f32x4){0.f, 0.f, 0.f, 0.f};

    // ones-column B fragment for denominator MFMA: B[k][n] = (n==0)
    s16x8 bones;
    {
        const short o = (m == 0) ? (short)0x3F80 : (short)0;
#pragma unroll
        for (int j = 0; j < 8; ++j) bones[j] = o;
    }

    // ---- register prefetch for super-step 0: lane owns row wave*16+m ----
    const float* fbase = features + (long long)(row_blk0 + wave * 16 + m) * D_;
    float4 pf[8];
#pragma unroll
    for (int ks = 0; ks < 4; ++ks) {
        pf[2 * ks]     = *(const float4*)(fbase + ks * 32 + kbase);
        pf[2 * ks + 1] = *(const float4*)(fbase + ks * 32 + kbase + 4);
    }
    int cv = 0;
    if (lane < 16) cv = ca[row_blk0 + wave * 16 + lane];

    __syncthreads();   // w1l ready (once; full drain here is harmless)

#pragma unroll
    for (int ss = 0; ss < NSS; ++ss) {
        // consume prefetch -> bf16 A-frags (compiler inserts counted vmcnt)
        s16x8 af[4];
#pragma unroll
        for (int ks = 0; ks < 4; ++ks) af[ks] = pk8(pf[2 * ks], pf[2 * ks + 1]);
        const int cvc = cv;

        // issue prefetch for next super-step; sched_barrier(0) pins the
        // issue point so the loads stay in flight through phases A+B
        // behind the non-draining raw barriers.
        if (ss + 1 < NSS) {
            const float* fn = fbase + (ss + 1) * 128 * D_;
#pragma unroll
            for (int ks = 0; ks < 4; ++ks) {
                pf[2 * ks]     = *(const float4*)(fn + ks * 32 + kbase);
                pf[2 * ks + 1] = *(const float4*)(fn + ks * 32 + kbase + 4);
            }
            if (lane < 16) cv = ca[row_blk0 + (ss + 1) * 128 + wave * 16 + lane];
        }
        __builtin_amdgcn_sched_barrier(0);

        // ---- phase A: stage ft (transposed bf16) + h-matmul + epilogue ----
        const int r = wave * 16 + m;   // row within 128-row super-tile
#pragma unroll
        for (int ks = 0; ks < 4; ++ks)
#pragma unroll
            for (int j = 0; j < 8; ++j)
                ft[(ks * 32 + kbase + j) * RST + r] = (unsigned short)af[ks][j];

        f32x4 hacc[4];
#pragma unroll
        for (int nt = 0; nt < 4; ++nt) hacc[nt] = (f32x4){0.f, 0.f, 0.f, 0.f};
#pragma unroll
        for (int ks = 0; ks < 4; ++ks)
#pragma unroll
            for (int nt = 0; nt < 4; ++nt) {
                const s16x8 w = *(const s16x8*)&w1l[(nt * 16 + m) * W1S +
                                                    ks * 32 + kbase];
                hacc[nt] = __builtin_amdgcn_mfma_f32_16x16x32_bf16(
                    af[ks], w, hacc[nt], 0, 0, 0);
            }

        // relu, @W2, sigmoid, e = exp(imp-1)   (HW-validated path)
        float p[4];
#pragma unroll
        for (int rr = 0; rr < 4; ++rr) {
            float sv = 0.f;
#pragma unroll
            for (int nt = 0; nt < 4; ++nt)
                sv = fmaf(fmaxf(hacc[nt][rr] + b1v[nt], 0.f), w2v[nt], sv);
#pragma unroll
            for (int off = 1; off < 16; off <<= 1)
                sv += __shfl_xor(sv, off, 64);
            const float pre = sv + b2v;
            const float imp = 1.f / (1.f + __expf(-pre));
            p[rr] = __expf(imp - 1.f);
        }
        const int q = lane & 3;
        const float prov = (q == 0) ? p[0] : (q == 1) ? p[1] : (q == 2) ? p[2] : p[3];
        const int srcl = ((m >> 2) << 4) | (m & 3);
        const float eL = __shfl(prov, srcl, 64);   // e for local row (lane&15)
        if (lane < 16)
            ceu[wave * 16 + lane] =
                ((unsigned)(unsigned short)bf16rne(eL) << 16) | (unsigned)cvc;

        // barrier A: LDS writes (ft, ceu) visible -> lgkmcnt(0) only.
        // vmcnt NOT drained: pf prefetch stays outstanding.
        asm volatile("s_waitcnt lgkmcnt(0)" ::: "memory");
        __builtin_amdgcn_s_barrier();

        // ---- phase B: every wave aggregates its (CH, dh) slice, 4 k-groups --
#pragma unroll
        for (int kg = 0; kg < 4; ++kg) {
            const uint4* cq = (const uint4*)&ceu[kg * 32 + kbase];
            const uint4 ua = cq[0], ub = cq[1];
            const unsigned uu[8] = {ua.x, ua.y, ua.z, ua.w, ub.x, ub.y, ub.z, ub.w};

            s16x8 afr;
#pragma unroll
            for (int j = 0; j < 8; ++j)
                afr[j] = ((int)(uu[j] & 0xFFu) == CH * 16 + m)
                             ? (short)(uu[j] >> 16) : (short)0;

#pragma unroll
            for (int nt = 0; nt < 4; ++nt) {
                const int d0 = (dh * 4 + nt) * 16 + m;
                const s16x8 bfv = *(const s16x8*)&ft[d0 * RST + kg * 32 + kbase];
                accS[nt] = __builtin_amdgcn_mfma_f32_16x16x32_bf16(
                    afr, bfv, accS[nt], 0, 0, 0);
            }
            if (dh == 0)
                accD = __builtin_amdgcn_mfma_f32_16x16x32_bf16(afr, bones, accD, 0, 0, 0);
        }

        // barrier B: phase-B LDS reads consumed into registers; bare barrier
        // orders next ss's ft writes.
        __builtin_amdgcn_s_barrier();
    }

    // ---- flush: per-wave slices disjoint -> plain stores (ws path) ----
#pragma unroll
    for (int nt = 0; nt < 4; ++nt)
#pragma unroll
        for (int qq = 0; qq < 4; ++qq) {
            const int idx = (CH * 16 + kb * 4 + qq) * D_ + (dh * 4 + nt) * 16 + m;
            if (USE_WS) pout[(size_t)bidx * (C_ * D_) + idx] = accS[nt][qq];
            else atomicAdd(&out_sums[b * (C_ * D_) + idx], accS[nt][qq]);
        }
    if (dh == 0 && m == 0) {
#pragma unroll
        for (int qq = 0; qq < 4; ++qq) {
            const int c = CH * 16 + kb * 4 + qq;
            if (USE_WS) pden[bidx * C_ + c] = accD[qq];
            else atomicAdd(&denoms[b * C_ + c], accD[qq]);
        }
    }
}

// Reduce SLICES partials per (b,c), divide by reduced denom, write out.
__global__ __launch_bounds__(512)
void ca_reduce_kernel(const float* __restrict__ pout,
                      const float* __restrict__ pden,
                      float* __restrict__ out)
{
    __shared__ float red[512];
    __shared__ float dns;

    const int bc = blockIdx.x;           // 0 .. B_*C_-1
    const int b  = bc >> 6;
    const int c  = bc & (C_ - 1);
    const int t  = threadIdx.x;
    const int d  = t & 127;
    const int sg = t >> 7;               // 0..3

    const float* pb = pout + ((size_t)(b * SLICES + sg * 16)) * (C_ * D_)
                           + c * D_ + d;
    float s = 0.f;
#pragma unroll 4
    for (int i = 0; i < 16; ++i) s += pb[(size_t)i * (C_ * D_)];
    red[t] = s;

    float dnv = 0.f;
    if (t < SLICES) dnv = pden[(b * SLICES + t) * C_ + c];
    if (t < 64) {
#pragma unroll
        for (int off = 32; off > 0; off >>= 1) dnv += __shfl_xor(dnv, off, 64);
        if (t == 0) dns = dnv;
    }
    __syncthreads();

    if (t < 128) {
        const float tot = red[t] + red[t + 128] + red[t + 256] + red[t + 384];
        const float dn = dns;
        out[(size_t)bc * D_ + t] = (dn > 0.f) ? (tot / dn) : 0.f;
    }
}

__global__ void ca_zero_kernel(float* __restrict__ out_sums,
                               float* __restrict__ denoms)
{
    const int i = blockIdx.x * blockDim.x + threadIdx.x;
    if (i < B_ * C_ * D_) out_sums[i] = 0.f;
    if (i < B_ * C_)      denoms[i] = 0.f;
}

__global__ void ca_finalize_kernel(float* __restrict__ out_sums,
                                   const float* __restrict__ denoms)
{
    const int i = blockIdx.x * blockDim.x + threadIdx.x;
    if (i >= B_ * C_ * D_) return;
    const int bc = i >> 7;
    const float den = denoms[bc];
    const float v = out_sums[i];
    out_sums[i] = (den > 0.f) ? (v / den) : 0.f;
}

extern "C" void kernel_launch(void* const* d_in, const int* in_sizes, int n_in,
                              void* d_out, int out_size, void* d_ws, size_t ws_size,
                              hipStream_t stream) {
    const float* features = (const float*)d_in[0];
    const int*   ca       = (const int*)  d_in[1];
    const float* W1       = (const float*)d_in[2];
    const float* b1       = (const float*)d_in[3];
    const float* W2       = (const float*)d_in[4];
    const float* b2       = (const float*)d_in[5];

    float* out = (float*)d_out;   // [B*C*D]

    // ws layout: [pden 128KB][pout 16MB]
    float* pden = (float*)d_ws;
    float* pout = (float*)((char*)d_ws + 131072);
    const size_t need_full = 131072 + (size_t)NBLOCKS * C_ * D_ * 4;

    if (ws_size >= need_full) {
        ca_fused_kernel<true><<<NBLOCKS, NTHREADS, 0, stream>>>(
            features, ca, b1, W2, b2, W1, nullptr, nullptr, pout, pden);
        ca_reduce_kernel<<<B_ * C_, 512, 0, stream>>>(pout, pden, out);
    } else {
        // fallback: global-atomic flush (needs only pden prefix, 2 KB)
        ca_zero_kernel<<<(B_ * C_ * D_ + 255) / 256, 256, 0, stream>>>(out, pden);
        ca_fused_kernel<false><<<NBLOCKS, NTHREADS, 0, stream>>>(
            features, ca, b1, W2, b2, W1, out, pden, nullptr, nullptr);
        ca_finalize_kernel<<<(B_ * C_ * D_ + 255) / 256, 256, 0, stream>>>(out, pden);
    }
}

// Round 18
// 45.269 us; speedup vs baseline: 1.3395x; 1.0448x over previous
//
#include <hip/hip_runtime.h>
#include <hip/hip_bf16.h>

// ClusterAggregator: B=8, N=32768, D=128, C=64, H=64
// out[b,c,:] = sum_{n: ca[b,n]==c} w_n * f[b,n,:], w = segment softmax of
// imp = sigmoid(relu(f@W1+b1)@W2+b2). Softmax shift-invariance: fixed shift 1.
//
// R18 = R17 frame (launch_bounds(512,2) -- the allocator fix that ended the
// VGPR=64 spill era -- + raw barriers + sched-pin) + R11's two LDS-pipe cuts,
// which were only ever measured UNDER the spill (R11/R13) and never with a
// real 128-reg file:
//  (1) ft staging via transpose-MFMA (C = af x identity-col B) -> 8
//      ds_write_b64 replace 32 ds_write_b16.
//  (2) swapped phase-A matmul h^T = W1^T @ f^T: row lands on lane ->
//      W2-reduce lane-local + 2 shfl_xor, ONE sigmoid/exp chain (was 4).
// LDS ops/wave/super-step ~86 -> ~47. Phase B / flush / reduce unchanged.

#define B_ 8
#define N_ 32768
#define D_ 128
#define C_ 64
#define H_ 64

#define NTHREADS 512
#define NWAVES 8
#define ROWS_PER_BLOCK 512
#define NBLOCKS ((B_ * N_) / ROWS_PER_BLOCK)   // 512
#define SLICES (NBLOCKS / B_)                  // 64
#define NSS 4                                  // super-steps of 128 rows
#define RST 152   // ft ushort stride (304 B; 16B-aligned)
#define W1S 136   // w1l ushort stride

typedef float f32x4 __attribute__((ext_vector_type(4)));
typedef short s16x8 __attribute__((ext_vector_type(8)));

__device__ __forceinline__ short bf16rne(float x) {
    unsigned u = __float_as_uint(x);
    u = (u + 0x7FFFu + ((u >> 16) & 1u)) >> 16;
    return (short)u;
}
__device__ __forceinline__ float ubf_lo(unsigned u) {
    return __uint_as_float(u << 16);
}
__device__ __forceinline__ float ubf_hi(unsigned u) {
    return __uint_as_float(u & 0xFFFF0000u);
}

__device__ __forceinline__ s16x8 pk8(float4 a, float4 b) {
    union { s16x8 v; __hip_bfloat162 h[4]; } u;
    u.h[0] = __float22bfloat162_rn(make_float2(a.x, a.y));
    u.h[1] = __float22bfloat162_rn(make_float2(a.z, a.w));
    u.h[2] = __float22bfloat162_rn(make_float2(b.x, b.y));
    u.h[3] = __float22bfloat162_rn(make_float2(b.z, b.w));
    return u.v;
}

template <bool USE_WS>
__global__ __launch_bounds__(NTHREADS, 2)   // min 2 waves/EU: frees allocator
void ca_fused_kernel(const float* __restrict__ features,
                     const int* __restrict__ ca,
                     const float* __restrict__ b1,
                     const float* __restrict__ W2,
                     const float* __restrict__ b2,
                     const float* __restrict__ W1,   // fp32 [128][64]
                     float* __restrict__ out_sums,   // atomic path: [B*C*D]
                     float* __restrict__ denoms,     // atomic path: [B*C]
                     float* __restrict__ pout,       // ws path: [NBLOCKS][C*D]
                     float* __restrict__ pden)       // ws path: [NBLOCKS][C]
{
    __shared__ __align__(16) unsigned short ft[D_ * RST];   // 38.9 KB bf16 f^T
    __shared__ __align__(16) unsigned short w1l[H_ * W1S];  // 17.4 KB bf16 W1^T
    __shared__ __align__(16) unsigned int ceu[128];         // packed (e|c)/row

    const int tid  = threadIdx.x;
    const int lane = tid & 63;
    const int wave = tid >> 6;
    const int m    = lane & 15;
    const int kb   = lane >> 4;
    const int kbase = kb * 8;
    const int bidx = blockIdx.x;
    const int b    = bidx / SLICES;
    const int row_blk0 = bidx * ROWS_PER_BLOCK;

    // W1 (fp32, coalesced) -> bf16 W1^T in LDS: w1l[h][k] = bf16(W1[k][h])
    for (int i = tid; i < H_ * D_; i += NTHREADS) {
        const int k = i >> 6, h = i & 63;
        w1l[h * W1S + k] = (unsigned short)bf16rne(W1[i]);
    }

    // per-lane epilogue constants: this lane's 16 hcols = c4*16 + kb*4 + q
    f32x4 w2v[4];          // fp32 (precision-critical)
    unsigned b1p[8];       // bf16-packed pairs (b1 == 0 here: exact)
#pragma unroll
    for (int c4 = 0; c4 < 4; ++c4) {
#pragma unroll
        for (int qq = 0; qq < 4; ++qq)
            w2v[c4][qq] = W2[c4 * 16 + kb * 4 + qq];
#pragma unroll
        for (int hh = 0; hh < 2; ++hh) {
            const int i0 = c4 * 16 + kb * 4 + hh * 2;
            b1p[c4 * 2 + hh] =
                ((unsigned)(unsigned short)bf16rne(b1[i0 + 1]) << 16) |
                (unsigned)(unsigned short)bf16rne(b1[i0]);
        }
    }
    const float b2v = b2[0];

    const int CH = wave >> 1;   // this wave's cluster chunk (16 clusters)
    const int dh = wave & 1;    // this wave's d-half (64 dims)

    f32x4 accS[4];
    f32x4 accD = (f32x4){0.f, 0.f, 0.f, 0.f};
#pragma unroll
    for (int nt = 0; nt < 4; ++nt) accS[nt] = (f32x4){0.f, 0.f, 0.f, 0.f};

    // ones-column B fragment for denominator MFMA: B[k][n] = (n==0)
    s16x8 bones;
    {
        const short o = (m == 0) ? (short)0x3F80 : (short)0;
#pragma unroll
        for (int j = 0; j < 8; ++j) bones[j] = o;
    }
    // identity-column B frags for the transpose MFMA:
    // bI0[k][n] = (k == n), bI1[k][n] = (k == 16+n)  (k = kb*8+j, n = m)
    s16x8 bI0, bI1;
#pragma unroll
    for (int j = 0; j < 8; ++j) {
        bI0[j] = (kbase + j == m)      ? (short)0x3F80 : (short)0;
        bI1[j] = (kbase + j == 16 + m) ? (short)0x3F80 : (short)0;
    }

    // register prefetch: lane owns row wave*16+m
    const float* fbase = features + (long long)(row_blk0 + wave * 16 + m) * D_;
    float4 pf[8];
#pragma unroll
    for (int ks = 0; ks < 4; ++ks) {
        pf[2 * ks]     = *(const float4*)(fbase + ks * 32 + kbase);
        pf[2 * ks + 1] = *(const float4*)(fbase + ks * 32 + kbase + 4);
    }
    int cv = 0;
    if (lane < 16) cv = ca[row_blk0 + wave * 16 + lane];

    __syncthreads();   // w1l ready (once; full drain harmless here)

#pragma unroll
    for (int ss = 0; ss < NSS; ++ss) {
        // consume prefetch -> bf16 A/B frags
        s16x8 af[4];
#pragma unroll
        for (int ks = 0; ks < 4; ++ks) af[ks] = pk8(pf[2 * ks], pf[2 * ks + 1]);
        const int cvc = cv;

        // issue prefetch for next super-step; pin issue point
        if (ss + 1 < NSS) {
            const float* fn = fbase + (ss + 1) * 128 * D_;
#pragma unroll
            for (int ks = 0; ks < 4; ++ks) {
                pf[2 * ks]     = *(const float4*)(fn + ks * 32 + kbase);
                pf[2 * ks + 1] = *(const float4*)(fn + ks * 32 + kbase + 4);
            }
            if (lane < 16) cv = ca[row_blk0 + (ss + 1) * 128 + wave * 16 + lane];
        }
        __builtin_amdgcn_sched_barrier(0);

        // ---- ft staging via transpose-MFMA + b64 writes ----
        // C = af x bI(sel): lane(m,kb) reg q = f[r=kb*4+q][ks*32+sel*16+m]
        // -> pack 4 r-consecutive bf16 -> ds_write_b64 at ft[d][wave*16+kb*4]
        const int rg0 = wave * 16 + kb * 4;
#pragma unroll
        for (int ks = 0; ks < 4; ++ks) {
            const f32x4 z = (f32x4){0.f, 0.f, 0.f, 0.f};
            const f32x4 t0 = __builtin_amdgcn_mfma_f32_16x16x32_bf16(af[ks], bI0, z, 0, 0, 0);
            const f32x4 t1 = __builtin_amdgcn_mfma_f32_16x16x32_bf16(af[ks], bI1, z, 0, 0, 0);
            union { uint2 u; __hip_bfloat162 h[2]; } p0, p1;
            p0.h[0] = __float22bfloat162_rn(make_float2(t0[0], t0[1]));
            p0.h[1] = __float22bfloat162_rn(make_float2(t0[2], t0[3]));
            p1.h[0] = __float22bfloat162_rn(make_float2(t1[0], t1[1]));
            p1.h[1] = __float22bfloat162_rn(make_float2(t1[2], t1[3]));
            *(uint2*)&ft[(ks * 32 + m) * RST + rg0]      = p0.u;
            *(uint2*)&ft[(ks * 32 + 16 + m) * RST + rg0] = p1.u;
        }

        // ---- phase A (swapped): h^T = W1^T @ f^T ----
        // A = w1l frag (lane m = hcol within chunk), B = af (lane m = row r).
        // C: lane(m,kb) reg q = h[r=m][hcol = c4*16 + kb*4 + q]
        float tp = 0.f;
#pragma unroll
        for (int c4 = 0; c4 < 4; ++c4) {
            f32x4 hc = (f32x4){0.f, 0.f, 0.f, 0.f};
#pragma unroll
            for (int ks = 0; ks < 4; ++ks) {
                const s16x8 w = *(const s16x8*)&w1l[(c4 * 16 + m) * W1S +
                                                    ks * 32 + kbase];
                hc = __builtin_amdgcn_mfma_f32_16x16x32_bf16(w, af[ks], hc, 0, 0, 0);
            }
            const float b0  = ubf_lo(b1p[c4 * 2]),     bb1 = ubf_hi(b1p[c4 * 2]);
            const float b2_ = ubf_lo(b1p[c4 * 2 + 1]), b3  = ubf_hi(b1p[c4 * 2 + 1]);
            tp = fmaf(fmaxf(hc[0] + b0,  0.f), w2v[c4][0], tp);
            tp = fmaf(fmaxf(hc[1] + bb1, 0.f), w2v[c4][1], tp);
            tp = fmaf(fmaxf(hc[2] + b2_, 0.f), w2v[c4][2], tp);
            tp = fmaf(fmaxf(hc[3] + b3,  0.f), w2v[c4][3], tp);
        }
        // reduce across kb groups: t for row r = m lands on every lane
        tp += __shfl_xor(tp, 16, 64);
        tp += __shfl_xor(tp, 32, 64);
        const float pre = tp + b2v;
        const float imp = 1.f / (1.f + __expf(-pre));
        const float e   = __expf(imp - 1.f);
        if (lane < 16)
            ceu[wave * 16 + lane] =
                ((unsigned)(unsigned short)bf16rne(e) << 16) | (unsigned)cvc;

        // barrier A: LDS writes (ft, ceu) visible -> lgkmcnt(0) only.
        asm volatile("s_waitcnt lgkmcnt(0)" ::: "memory");
        __builtin_amdgcn_s_barrier();

        // ---- phase B: every wave aggregates its (CH, dh) slice, 4 k-groups --
#pragma unroll
        for (int kg = 0; kg < 4; ++kg) {
            const uint4* cq = (const uint4*)&ceu[kg * 32 + kbase];
            const uint4 ua = cq[0], ub = cq[1];
            const unsigned uu[8] = {ua.x, ua.y, ua.z, ua.w, ub.x, ub.y, ub.z, ub.w};

            s16x8 afr;
#pragma unroll
            for (int j = 0; j < 8; ++j)
                afr[j] = ((int)(uu[j] & 0xFFu) == CH * 16 + m)
                             ? (short)(uu[j] >> 16) : (short)0;

#pragma unroll
            for (int nt = 0; nt < 4; ++nt) {
                const int d0 = (dh * 4 + nt) * 16 + m;
                const s16x8 bfv = *(const s16x8*)&ft[d0 * RST + kg * 32 + kbase];
                accS[nt] = __builtin_amdgcn_mfma_f32_16x16x32_bf16(
                    afr, bfv, accS[nt], 0, 0, 0);
            }
            if (dh == 0)
                accD = __builtin_amdgcn_mfma_f32_16x16x32_bf16(afr, bones, accD, 0, 0, 0);
        }

        // barrier B: phase-B LDS reads consumed into registers
        __builtin_amdgcn_s_barrier();
    }

    // ---- flush: per-wave slices disjoint -> plain stores (ws path) ----
#pragma unroll
    for (int nt = 0; nt < 4; ++nt)
#pragma unroll
        for (int qq = 0; qq < 4; ++qq) {
            const int idx = (CH * 16 + kb * 4 + qq) * D_ + (dh * 4 + nt) * 16 + m;
            if (USE_WS) pout[(size_t)bidx * (C_ * D_) + idx] = accS[nt][qq];
            else atomicAdd(&out_sums[b * (C_ * D_) + idx], accS[nt][qq]);
        }
    if (dh == 0 && m == 0) {
#pragma unroll
        for (int qq = 0; qq < 4; ++qq) {
            const int c = CH * 16 + kb * 4 + qq;
            if (USE_WS) pden[bidx * C_ + c] = accD[qq];
            else atomicAdd(&denoms[b * C_ + c], accD[qq]);
        }
    }
}

// Reduce SLICES partials per (b,c), divide by reduced denom, write out.
__global__ __launch_bounds__(512)
void ca_reduce_kernel(const float* __restrict__ pout,
                      const float* __restrict__ pden,
                      float* __restrict__ out)
{
    __shared__ float red[512];
    __shared__ float dns;

    const int bc = blockIdx.x;           // 0 .. B_*C_-1
    const int b  = bc >> 6;
    const int c  = bc & (C_ - 1);
    const int t  = threadIdx.x;
    const int d  = t & 127;
    const int sg = t >> 7;               // 0..3

    const float* pb = pout + ((size_t)(b * SLICES + sg * 16)) * (C_ * D_)
                           + c * D_ + d;
    float s = 0.f;
#pragma unroll 4
    for (int i = 0; i < 16; ++i) s += pb[(size_t)i * (C_ * D_)];
    red[t] = s;

    float dnv = 0.f;
    if (t < SLICES) dnv = pden[(b * SLICES + t) * C_ + c];
    if (t < 64) {
#pragma unroll
        for (int off = 32; off > 0; off >>= 1) dnv += __shfl_xor(dnv, off, 64);
        if (t == 0) dns = dnv;
    }
    __syncthreads();

    if (t < 128) {
        const float tot = red[t] + red[t + 128] + red[t + 256] + red[t + 384];
        const float dn = dns;
        out[(size_t)bc * D_ + t] = (dn > 0.f) ? (tot / dn) : 0.f;
    }
}

__global__ void ca_zero_kernel(float* __restrict__ out_sums,
                               float* __restrict__ denoms)
{
    const int i = blockIdx.x * blockDim.x + threadIdx.x;
    if (i < B_ * C_ * D_) out_sums[i] = 0.f;
    if (i < B_ * C_)      denoms[i] = 0.f;
}

__global__ void ca_finalize_kernel(float* __restrict__ out_sums,
                                   const float* __restrict__ denoms)
{
    const int i = blockIdx.x * blockDim.x + threadIdx.x;
    if (i >= B_ * C_ * D_) return;
    const int bc = i >> 7;
    const float den = denoms[bc];
    const float v = out_sums[i];
    out_sums[i] = (den > 0.f) ? (v / den) : 0.f;
}

extern "C" void kernel_launch(void* const* d_in, const int* in_sizes, int n_in,
                              void* d_out, int out_size, void* d_ws, size_t ws_size,
                              hipStream_t stream) {
    const float* features = (const float*)d_in[0];
    const int*   ca       = (const int*)  d_in[1];
    const float* W1       = (const float*)d_in[2];
    const float* b1       = (const float*)d_in[3];
    const float* W2       = (const float*)d_in[4];
    const float* b2       = (const float*)d_in[5];

    float* out = (float*)d_out;   // [B*C*D]

    // ws layout: [pden 128KB][pout 16MB]
    float* pden = (float*)d_ws;
    float* pout = (float*)((char*)d_ws + 131072);
    const size_t need_full = 131072 + (size_t)NBLOCKS * C_ * D_ * 4;

    if (ws_size >= need_full) {
        ca_fused_kernel<true><<<NBLOCKS, NTHREADS, 0, stream>>>(
            features, ca, b1, W2, b2, W1, nullptr, nullptr, pout, pden);
        ca_reduce_kernel<<<B_ * C_, 512, 0, stream>>>(pout, pden, out);
    } else {
        // fallback: global-atomic flush (needs only pden prefix, 2 KB)
        ca_zero_kernel<<<(B_ * C_ * D_ + 255) / 256, 256, 0, stream>>>(out, pden);
        ca_fused_kernel<false><<<NBLOCKS, NTHREADS, 0, stream>>>(
            features, ca, b1, W2, b2, W1, out, pden, nullptr, nullptr);
        ca_finalize_kernel<<<(B_ * C_ * D_ + 255) / 256, 256, 0, stream>>>(out, pden);
    }
}